// Round 7
// baseline (83.484 us; speedup 1.0000x reference)
//
#include <hip/hip_runtime.h>
#include <math.h>

#define NFRAMES 16384
#define NJOINTS 22
#define NPATHS  5
#define NPAIRS  (NPATHS * NPATHS)
#define NSEG    16      // segments per motion: 3+3+4+3+3
#define FSTR    (NJOINTS * 3)   // 66 floats per frame per motion
#define FPB     8       // OUTPUT frames per block (one wave); +1 halo frame

typedef float v4f __attribute__((ext_vector_type(4)));

// Per-segment float offsets (joint*3) into a frame: {start, end}.
// path0 (2,5)(5,8)(8,11); path1 (1,4)(4,7)(7,10);
// path2 (3,6)(6,9)(9,12)(12,15); path3 (14,17)(17,19)(19,21);
// path4 (13,16)(16,18)(18,20).
__constant__ int2 c_seg[NSEG] = {
    {6,15},{15,24},{24,33},
    {3,12},{12,21},{21,30},
    {9,18},{18,27},{27,36},{36,45},
    {42,51},{51,57},{57,63},
    {39,48},{48,54},{54,60}
};
__constant__ int c_pstart[NPATHS] = {0, 3, 6, 10, 13};
__constant__ int c_plen[NPATHS]   = {3, 3, 4, 3, 3};

// ---------- packed 4-frame math ----------
struct V3 { v4f x, y, z; };
__device__ __forceinline__ V3 vsub(V3 a, V3 b) { V3 r; r.x=a.x-b.x; r.y=a.y-b.y; r.z=a.z-b.z; return r; }
__device__ __forceinline__ v4f vdot(V3 a, V3 b) { return a.x*b.x + a.y*b.y + a.z*b.z; }
__device__ __forceinline__ V3 vcross(V3 a, V3 b) {
    V3 r;
    r.x = a.y*b.z - a.z*b.y;
    r.y = a.z*b.x - a.x*b.z;
    r.z = a.x*b.y - a.y*b.x;
    return r;
}

// asin(clamp(d * rsqrt(m), -1, 1)) with jnp safe-normalize semantics.
// m = q_i*q_j >= 0; m == 0 -> 0 via final guard. Degenerate: rsq(0)=inf,
// min(|x|,1) -> 1 (v_min returns non-NaN operand), finite, then zeroed.
// asin core via A&S 4.4.45 (degree-3): |eps| <= 6.7e-5 rad.
__device__ __forceinline__ v4f vasin_term(v4f d, v4f m) {
    v4f rs;
#pragma unroll
    for (int i = 0; i < 4; i++) rs[i] = __builtin_amdgcn_rsqf(m[i]);
    v4f x = d * rs;
    v4f one = 1.0f;
    v4f a = __builtin_elementwise_max(x, -x);
    a = __builtin_elementwise_min(a, one);
    v4f p = a * -0.0187293f + 0.0742610f;
    p = a * p + -0.2121144f;
    p = a * p + 1.5707288f;
    v4f om = one - a;
    v4f s;
#pragma unroll
    for (int i = 0; i < 4; i++) s[i] = __builtin_amdgcn_sqrtf(om[i]);
    v4f r = 1.5707963268f - s * p;
#pragma unroll
    for (int i = 0; i < 4; i++) {
        float ri = (x[i] < 0.0f) ? -r[i] : r[i];
        r[i] = (m[i] > 0.0f) ? ri : 0.0f;
    }
    return r;
}

// ---------- scalar (halo frame) math ----------
struct S3 { float x, y, z; };
__device__ __forceinline__ S3 ssub(S3 a, S3 b) { return S3{a.x-b.x, a.y-b.y, a.z-b.z}; }
__device__ __forceinline__ float sdot(S3 a, S3 b) { return fmaf(a.x, b.x, fmaf(a.y, b.y, a.z*b.z)); }
__device__ __forceinline__ S3 scross(S3 a, S3 b) {
    return S3{ fmaf(a.y, b.z, -a.z*b.y), fmaf(a.z, b.x, -a.x*b.z), fmaf(a.x, b.y, -a.y*b.x) };
}
__device__ __forceinline__ float asin_term_s(float d, float m) {
    float rs = __builtin_amdgcn_rsqf(m);
    float x = d * rs;
    float a = fminf(fabsf(x), 1.0f);
    float p = fmaf(a, -0.0187293f, 0.0742610f);
    p = fmaf(a, p, -0.2121144f);
    p = fmaf(a, p, 1.5707288f);
    float s = __builtin_amdgcn_sqrtf(1.0f - a);
    float r = fmaf(-s, p, 1.5707963268f);
    r = (x < 0.0f) ? -r : r;
    return (m > 0.0f) ? r : 0.0f;
}

__device__ __forceinline__ v4f shfl_xor_v4(v4f v, int mask, int width) {
    v4f r;
#pragma unroll
    for (int i = 0; i < 4; i++) r[i] = __shfl_xor(v[i], mask, width);
    return r;
}

// bbox overlap butterfly over (half = motion, jj = joint) lane layout.
// Returns 4 bits (component r -> bit r) valid in lane 0, 0 elsewhere.
__device__ __forceinline__ int bbox4(v4f x, v4f z, int l) {
    v4f xn = x, xx = x, zn = z, zx = z;
#pragma unroll
    for (int k = 1; k < 32; k <<= 1) {
        xn = __builtin_elementwise_min(xn, shfl_xor_v4(xn, k, 32));
        xx = __builtin_elementwise_max(xx, shfl_xor_v4(xx, k, 32));
        zn = __builtin_elementwise_min(zn, shfl_xor_v4(zn, k, 32));
        zx = __builtin_elementwise_max(zx, shfl_xor_v4(zx, k, 32));
    }
    v4f oxn = shfl_xor_v4(xn, 32, 64);
    v4f oxx = shfl_xor_v4(xx, 32, 64);
    v4f ozn = shfl_xor_v4(zn, 32, 64);
    v4f ozx = shfl_xor_v4(zx, 32, 64);
    int bits = 0;
    if (l == 0) {
#pragma unroll
        for (int r = 0; r < 4; r++) {
            bool vx = !((xx[r] < oxn[r]) || (oxx[r] < xn[r]));
            bool vz = !((zx[r] < ozn[r]) || (ozx[r] < zn[r]));
            if (vx && vz) bits |= 1 << r;
        }
    }
    return bits;
}

// 256 GLI terms for 4 packed frames: lane l does terms l+64k.
__device__ __forceinline__ void gli_terms_v4(const v4f* sF, v4f* sT, int l,
                                             int2 o2, const int2* o1s) {
    const v4f* B = sF + FSTR;
    V3 s2; s2.x = B[o2.x]; s2.y = B[o2.x+1]; s2.z = B[o2.x+2];
    V3 e2; e2.x = B[o2.y]; e2.y = B[o2.y+1]; e2.z = B[o2.y+2];
#pragma unroll
    for (int k = 0; k < 4; k++) {
        int2 o1 = o1s[k];
        V3 s1; s1.x = sF[o1.x]; s1.y = sF[o1.x+1]; s1.z = sF[o1.x+2];
        V3 e1; e1.x = sF[o1.y]; e1.y = sF[o1.y+1]; e1.z = sF[o1.y+2];

        V3 r12 = vsub(e1, s1);
        V3 r13 = vsub(s2, s1);
        V3 r14 = vsub(e2, s1);

        V3 f0v = vcross(r13, r14);
        V3 c1  = vcross(r12, r13);
        V3 c2  = vcross(r12, r14);
        v4f sg = -vdot(c2, r13);
        V3 f2  = vsub(vsub(c2, c1), f0v);

        v4f q0 = vdot(f0v, f0v);
        v4f q1 = vdot(c2, c2);
        v4f q2 = vdot(f2, f2);
        v4f q3 = vdot(c1, c1);
        v4f d0 =  vdot(f0v, c2);
        v4f d1 =  vdot(c2, f2);
        v4f d2 = -vdot(f2, c1);
        v4f d3 = -vdot(c1, f0v);

        v4f g = vasin_term(d0, q0 * q1)
              + vasin_term(d1, q1 * q2)
              + vasin_term(d2, q2 * q3)
              + vasin_term(d3, q3 * q0);

        v4f res;
#pragma unroll
        for (int r = 0; r < 4; r++) res[r] = (sg[r] > 0.0f) ? g[r] : -g[r];
        sT[l + 64 * k] = res;
    }
}

// Scalar halo frame: same term mapping.
__device__ __forceinline__ void gli_terms_s(const float* sF, float* sT, int l,
                                            int2 o2, const int2* o1s) {
    const float* B = sF + FSTR;
    S3 s2{B[o2.x], B[o2.x+1], B[o2.x+2]};
    S3 e2{B[o2.y], B[o2.y+1], B[o2.y+2]};
#pragma unroll
    for (int k = 0; k < 4; k++) {
        int2 o1 = o1s[k];
        S3 s1{sF[o1.x], sF[o1.x+1], sF[o1.x+2]};
        S3 e1{sF[o1.y], sF[o1.y+1], sF[o1.y+2]};
        S3 r12 = ssub(e1, s1), r13 = ssub(s2, s1), r14 = ssub(e2, s1);
        S3 f0v = scross(r13, r14), c1 = scross(r12, r13), c2 = scross(r12, r14);
        float sg = -sdot(c2, r13);
        S3 f2 = ssub(ssub(c2, c1), f0v);
        float q0 = sdot(f0v, f0v), q1 = sdot(c2, c2), q2 = sdot(f2, f2), q3 = sdot(c1, c1);
        float d0 = sdot(f0v, c2), d1 = sdot(c2, f2), d2 = -sdot(f2, c1), d3 = -sdot(c1, f0v);
        float g = asin_term_s(d0, q0*q1) + asin_term_s(d1, q1*q2)
                + asin_term_s(d2, q2*q3) + asin_term_s(d3, q3*q0);
        sT[l + 64*k] = (sg > 0.0f) ? g : -g;
    }
}

__device__ __forceinline__ v4f bin_reduce_v4(const v4f* sT, int ia0, int na, int ib0, int nb) {
    v4f s = v4f{0.0f, 0.0f, 0.0f, 0.0f};
#pragma unroll
    for (int ka = 0; ka < 4; ka++)
#pragma unroll
        for (int kb = 0; kb < 4; kb++) {
            int idx = (ka < na && kb < nb) ? ((ia0 + ka) * 16 + (ib0 + kb)) : 256;
            s += sT[idx];
        }
    return s * 0.07957747154594767f;   // 1/(4*pi)
}
__device__ __forceinline__ float bin_reduce_s(const float* sT, int ia0, int na, int ib0, int nb) {
    float s = 0.0f;
#pragma unroll
    for (int ka = 0; ka < 4; ka++)
#pragma unroll
        for (int kb = 0; kb < 4; kb++) {
            int idx = (ka < na && kb < nb) ? ((ia0 + ka) * 16 + (ib0 + kb)) : 256;
            s += sT[idx];
        }
    return s * 0.07957747154594767f;
}

__device__ __forceinline__ void stage4(const float* src, v4f* dst, int l) {
    v4f v;
#pragma unroll
    for (int r = 0; r < 4; r++) v[r] = src[r * FSTR + l];
    dst[l] = v;
    if (l < FSTR - 64) {                 // l < 2 -> coords 64, 65
        int co = 64 + l;
        v4f w;
#pragma unroll
        for (int r = 0; r < 4; r++) w[r] = src[r * FSTR + co];
        dst[co] = w;
    }
}

// FUSED kernel: ONE WAVE per block computes gli for frames F..F+8 (8 owned +
// 1 halo) and ov for F-1..F+9 (outer two read straight from global, range-
// zeroed), then produces out[F..F+7] entirely in-register/LDS. No workspace,
// no second kernel, no gli/ov global round-trip. blockDim == wavefront ==>
// every __syncthreads compiles to a waitcnt only (single-wave workgroup);
// wave-lockstep makes the LDS reuse between passes safe.
__global__ __launch_bounds__(64, 2) void k_fused(const float* __restrict__ m1,
                                                 const float* __restrict__ m2,
                                                 float* __restrict__ out) {
    __shared__ v4f   sF4a[2 * FSTR];   // frames F..F+3, coord-major packed
    __shared__ v4f   sF4b[2 * FSTR];   // frames F+4..F+7
    __shared__ float sFh[2 * FSTR];    // halo frame F+8 (clamped)
    __shared__ v4f   sT4[260];         // term buffer (reused A then B); [256]=0
    __shared__ float sTh[260];         // halo term buffer; [256]=0

    int l = threadIdx.x;
    int F = blockIdx.x * FPB;
    const float* a = m1 + (size_t)F * FSTR;
    const float* b = m2 + (size_t)F * FSTR;

    // Hoisted divergent-index constant loads.
    int jseg = l & 15;
    int i0 = l >> 4;
    int2 o2 = c_seg[jseg];
    int2 o1s[4];
#pragma unroll
    for (int k = 0; k < 4; k++) o1s[k] = c_seg[i0 + 4 * k];

    // Bin-reduce params (na=0 for lanes >= 25 -> pad-only gathers -> 0).
    int ia0 = 0, na = 0, ib0 = 0, nb = 0;
    if (l < NPAIRS) {
        int pa = (l * 205) >> 10;   // l/5
        int pb = l - pa * 5;        // l%5
        ia0 = c_pstart[pa]; na = c_plen[pa];
        ib0 = c_pstart[pb]; nb = c_plen[pb];
    }

    // ---- stage 9 frames (halo clamped; only last block clamps) ----
    stage4(a, sF4a, l);
    stage4(b, sF4a + FSTR, l);
    stage4(a + 4 * FSTR, sF4b, l);
    stage4(b + 4 * FSTR, sF4b + FSTR, l);
    {
        int hf = F + 8; if (hf > NFRAMES - 1) hf = NFRAMES - 1;
        const float* ah = m1 + (size_t)hf * FSTR;
        const float* bh = m2 + (size_t)hf * FSTR;
        sFh[l] = ah[l];
        sFh[FSTR + l] = bh[l];
        if (l < FSTR - 64) {
            sFh[64 + l] = ah[64 + l];
            sFh[FSTR + 64 + l] = bh[64 + l];
        }
    }
    if (l == 32) sT4[256] = v4f{0.0f, 0.0f, 0.0f, 0.0f};
    if (l == 33) sTh[256] = 0.0f;
    __syncthreads();

    // ---- ov bits for frames F-1 .. F+9 (bit i = frame F-1+i) ----
    int half = l >> 5;
    int jj = l & 31; if (jj > NJOINTS - 1) jj = NJOINTS - 1;
    int ovbits = 0;
    {   // pass A: frames F..F+3 -> bits 1..4
        const v4f* p = sF4a + half * FSTR;
        ovbits |= bbox4(p[jj*3 + 0], p[jj*3 + 2], l) << 1;
    }
    {   // pass B: frames F+4..F+7 -> bits 5..8
        const v4f* p = sF4b + half * FSTR;
        ovbits |= bbox4(p[jj*3 + 0], p[jj*3 + 2], l) << 5;
    }
    {   // pass C: comp0 = F-1 (global), comp1 = F+8 (LDS), comp2 = F+9 (global)
        const float* gb = half ? m2 : m1;
        int fm1 = (F > 0) ? F - 1 : 0;
        int fp9 = F + 9; if (fp9 > NFRAMES - 1) fp9 = NFRAMES - 1;
        float xm1 = gb[(size_t)fm1 * FSTR + jj*3];
        float zm1 = gb[(size_t)fm1 * FSTR + jj*3 + 2];
        float x8  = sFh[half * FSTR + jj*3];
        float z8  = sFh[half * FSTR + jj*3 + 2];
        float x9  = gb[(size_t)fp9 * FSTR + jj*3];
        float z9  = gb[(size_t)fp9 * FSTR + jj*3 + 2];
        v4f x{xm1, x8, x9, x8};
        v4f z{zm1, z8, z9, z8};
        int bc = bbox4(x, z, l);
        if (l == 0) {
            if (F > 0                 && (bc & 1)) ovbits |= 1 << 0;
            if (F + 8 <= NFRAMES - 1  && (bc & 2)) ovbits |= 1 << 9;
            if (F + 9 <= NFRAMES - 1  && (bc & 4)) ovbits |= 1 << 10;
        }
    }

    // ---- GLI: pass A, pass B (sT4 reused), scalar halo ----
    gli_terms_v4(sF4a, sT4, l, o2, o1s);
    __syncthreads();
    v4f gA = bin_reduce_v4(sT4, ia0, na, ib0, nb);
    __syncthreads();                       // drain reads before sT4 reuse
    gli_terms_v4(sF4b, sT4, l, o2, o1s);
    gli_terms_s(sFh, sTh, l, o2, o1s);     // independent buffer, can overlap
    __syncthreads();
    v4f gB = bin_reduce_v4(sT4, ia0, na, ib0, nb);
    float gh = bin_reduce_s(sTh, ia0, na, ib0, nb);

    // ---- masks + diffs + 64-lane max reduce ----
    ovbits = __shfl(ovbits, 0, 64);
    float mk[9];
#pragma unroll
    for (int r = 0; r < 9; r++) mk[r] = ((ovbits >> r) & 7) ? 1.0f : 0.0f;
    float g[9];
#pragma unroll
    for (int r = 0; r < 4; r++) { g[r] = gA[r]; g[4 + r] = gB[r]; }
    g[8] = gh;                              // lanes >= 25 hold zeros throughout
    float d[8];
#pragma unroll
    for (int r = 0; r < 8; r++) d[r] = fabsf(g[r + 1] * mk[r + 1] - g[r] * mk[r]);
#pragma unroll
    for (int k = 1; k < 64; k <<= 1) {
#pragma unroll
        for (int r = 0; r < 8; r++) d[r] = fmaxf(d[r], __shfl_xor(d[r], k, 64));
    }
    if (l == 0) {
        *(float4*)(out + F) = float4{d[0], d[1], d[2], d[3]};
        if (F + FPB < NFRAMES) {            // all blocks except the last
            *(float4*)(out + F + 4) = float4{d[4], d[5], d[6], d[7]};
        } else {                            // last block: out has no f = NFRAMES-1
            out[F + 4] = d[4];
            out[F + 5] = d[5];
            out[F + 6] = d[6];
        }
    }
}

extern "C" void kernel_launch(void* const* d_in, const int* in_sizes, int n_in,
                              void* d_out, int out_size, void* d_ws, size_t ws_size,
                              hipStream_t stream) {
    const float* m1 = (const float*)d_in[0];
    const float* m2 = (const float*)d_in[1];
    float* out = (float*)d_out;
    (void)d_ws; (void)ws_size;              // fully fused: no workspace needed

    k_fused<<<NFRAMES / FPB, 64, 0, stream>>>(m1, m2, out);
}

// Round 8
// 80.122 us; speedup vs baseline: 1.0420x; 1.0420x over previous
//
#include <hip/hip_runtime.h>
#include <math.h>

#define NFRAMES 16384
#define NJOINTS 22
#define NPATHS  5
#define NPAIRS  (NPATHS * NPATHS)
#define NSEG    16      // segments per motion: 3+3+4+3+3
#define GSTRIDE 32      // padded gli row stride (floats) -> 128B-aligned rows
#define FSTR    (NJOINTS * 3)   // 66 floats per frame per motion
#define FPB     8       // frames per block (2 per wave, 4 waves)

typedef float v2f __attribute__((ext_vector_type(2)));

// Per-segment float offsets (joint*3) into a frame: {start, end}.
// path0 (2,5)(5,8)(8,11); path1 (1,4)(4,7)(7,10);
// path2 (3,6)(6,9)(9,12)(12,15); path3 (14,17)(17,19)(19,21);
// path4 (13,16)(16,18)(18,20).
__constant__ int2 c_seg[NSEG] = {
    {6,15},{15,24},{24,33},
    {3,12},{12,21},{21,30},
    {9,18},{18,27},{27,36},{36,45},
    {42,51},{51,57},{57,63},
    {39,48},{48,54},{54,60}
};
__constant__ int c_pstart[NPATHS] = {0, 3, 6, 10, 13};
__constant__ int c_plen[NPATHS]   = {3, 3, 4, 3, 3};

// Packed 2-frame 3-vector: .x/.y/.z are v2f holding {frameA, frameB}.
struct V3 { v2f x, y, z; };
__device__ __forceinline__ V3 vsub(V3 a, V3 b) { V3 r; r.x=a.x-b.x; r.y=a.y-b.y; r.z=a.z-b.z; return r; }
__device__ __forceinline__ v2f vdot(V3 a, V3 b) { return a.x*b.x + a.y*b.y + a.z*b.z; }
__device__ __forceinline__ V3 vcross(V3 a, V3 b) {
    V3 r;
    r.x = a.y*b.z - a.z*b.y;
    r.y = a.z*b.x - a.x*b.z;
    r.z = a.x*b.y - a.y*b.x;
    return r;
}

// asin(clamp(d * rsqrt(m), -1, 1)) with jnp safe-normalize semantics.
// m = q_i*q_j (product of squared face norms, >= 0). Zero norm (m == 0)
// -> normalized vec = 0 -> dot 0 -> asin 0. Degenerate path: rsq(0)=inf,
// x = +-inf or NaN; a = min(max(x,-x), 1) lands at 1 (v_min returns the
// non-NaN operand), result finite, then zeroed by the m>0 select.
// asin core via A&S 4.4.45 (degree-3): |eps| <= 6.7e-5 rad.
__device__ __forceinline__ v2f vasin_term(v2f d, v2f m) {
    v2f rs;
    rs.x = __builtin_amdgcn_rsqf(m.x);
    rs.y = __builtin_amdgcn_rsqf(m.y);
    v2f x = d * rs;
    v2f one = 1.0f;
    v2f a = __builtin_elementwise_max(x, -x);       // |x|
    a = __builtin_elementwise_min(a, one);          // one-sided clamp is enough
    v2f p = a * -0.0187293f + 0.0742610f;
    p = a * p + -0.2121144f;
    p = a * p + 1.5707288f;
    v2f om = one - a;
    v2f s;
    s.x = __builtin_amdgcn_sqrtf(om.x);
    s.y = __builtin_amdgcn_sqrtf(om.y);
    v2f r = 1.5707963268f - s * p;
    r.x = (x.x < 0.0f) ? -r.x : r.x;
    r.y = (x.y < 0.0f) ? -r.y : r.y;
    r.x = (m.x > 0.0f) ? r.x : 0.0f;                // safe-normalize guard on product
    r.y = (m.y > 0.0f) ? r.y : 0.0f;
    return r;
}

__device__ __forceinline__ v2f shfl_xor_v2(v2f v, int mask, int width) {
    v2f r;
    r.x = __shfl_xor(v.x, mask, width);
    r.y = __shfl_xor(v.y, mask, width);
    return r;
}

// One block (256 threads = 4 waves) per EIGHT frames; wave w owns the packed
// frame pair (f0+2w, f0+2w+1) end-to-end in its private LDS region:
//  - lane-coalesced staging of 2x132 floats into [motion][coord]{fr0,fr1} v2f
//  - lane l computes 4 GLI terms t = l+64k (j = l&15 shared -> motion2
//    fragment loaded once); packed fp32 over the 2 frames
//  - bbox overlap packed over the frame pair via width-32 shuffle
//    butterflies (lanes 0..31: motion1, 32..63: motion2) + width-64 swap
//  - lanes 0..24 bin-reduce via the unrolled padded v2f gather
// Two balanced __syncthreads (verified-baseline structure).
__global__ __launch_bounds__(256, 4) void k_gli(const float* __restrict__ m1,
                                                const float* __restrict__ m2,
                                                float* __restrict__ gli,
                                                int* __restrict__ ov) {
    __shared__ v2f sF[4][2 * FSTR];   // [wave][motion*66+coord], comps = 2 frames
    __shared__ v2f sT[4][260];        // [wave][term]; [256] = 0 pad

    int t = threadIdx.x;
    int w = t >> 6;
    int l = t & 63;
    int fp = blockIdx.x * FPB + 2 * w;          // first frame of this wave's pair
    const float* a = m1 + (size_t)fp * FSTR;    // 132 consecutive floats (2 frames)
    const float* b = m2 + (size_t)fp * FSTR;

    v2f* sFw = sF[w];
    float* sFf = (float*)sFw;

    // Hoist all divergent-index __constant__ loads for this lane up front:
    // j = l&15 fixed (motion2 segment), i = (l>>4)+4k over 4 iters.
    int j = l & 15;
    int i0 = l >> 4;
    int2 o2 = c_seg[j];
    int2 o1s[4];
#pragma unroll
    for (int k = 0; k < 4; k++) o1s[k] = c_seg[i0 + 4 * k];

    // Stage 132 floats per motion: u = l, l+64, (+128 for l<4).
    // float u -> frame fr = u>=66, coord co = u-66*fr; LDS float offset
    // motion1: 2*co+fr, motion2: 132 + 2*co+fr. Stride-2 writes: free 2-way.
    {
        int u1 = l + 64;
        int fr1 = (u1 >= FSTR) ? 1 : 0;
        int co1 = u1 - fr1 * FSTR;
        float a0v = a[l], a1v = a[u1];
        float b0v = b[l], b1v = b[u1];
        sFf[2 * l] = a0v;                       // u0=l: fr=0, co=l
        sFf[2 * co1 + fr1] = a1v;
        sFf[2 * FSTR + 2 * l] = b0v;
        sFf[2 * FSTR + 2 * co1 + fr1] = b1v;
        if (l < 2 * FSTR - 128) {               // u2 = l+128 in [128,132)
            int u2 = l + 128;
            int co2 = u2 - FSTR;                // fr=1
            sFf[2 * co2 + 1] = a[u2];
            sFf[2 * FSTR + 2 * co2 + 1] = b[u2];
        }
        if (l == 32) sT[w][256] = v2f{0.0f, 0.0f};
    }
    __syncthreads();

    // bbox overlap, packed over the frame pair — placed right after the
    // barrier so its (trans-free) shuffle chain can interleave with the
    // term phase's ds_reads in the scheduler window.
    {
        int half = l >> 5;                   // 0: motion1, 1: motion2
        int jj = l & 31;
        if (jj > NJOINTS - 1) jj = NJOINTS - 1;  // pad lanes replicate joint 21
        const v2f* p = sFw + half * FSTR;
        v2f x = p[jj * 3 + 0];
        v2f z = p[jj * 3 + 2];
        v2f xn = x, xx = x, zn = z, zx = z;
#pragma unroll
        for (int k = 1; k < 32; k <<= 1) {
            xn = __builtin_elementwise_min(xn, shfl_xor_v2(xn, k, 32));
            xx = __builtin_elementwise_max(xx, shfl_xor_v2(xx, k, 32));
            zn = __builtin_elementwise_min(zn, shfl_xor_v2(zn, k, 32));
            zx = __builtin_elementwise_max(zx, shfl_xor_v2(zx, k, 32));
        }
        v2f oxn = shfl_xor_v2(xn, 32, 64);
        v2f oxx = shfl_xor_v2(xx, 32, 64);
        v2f ozn = shfl_xor_v2(zn, 32, 64);
        v2f ozx = shfl_xor_v2(zx, 32, 64);
        if (l == 0) {
            int2 o;
            bool vx0 = !((xx.x < oxn.x) || (oxx.x < xn.x));
            bool vz0 = !((zx.x < ozn.x) || (ozx.x < zn.x));
            bool vx1 = !((xx.y < oxn.y) || (oxx.y < xn.y));
            bool vz1 = !((zx.y < ozn.y) || (ozx.y < zn.y));
            o.x = (vx0 && vz0) ? 1 : 0;
            o.y = (vx1 && vz1) ? 1 : 0;
            *(int2*)(ov + fp) = o;          // fp is even -> 8B aligned
        }
    }

    // 4 GLI terms per lane: t = l + 64k -> i = (l>>4)+4k, j = l&15 (fixed).
    {
        const v2f* B = sFw + FSTR;
        V3 s2; s2.x = B[o2.x]; s2.y = B[o2.x+1]; s2.z = B[o2.x+2];
        V3 e2; e2.x = B[o2.y]; e2.y = B[o2.y+1]; e2.z = B[o2.y+2];
#pragma unroll
        for (int k = 0; k < 4; k++) {
            int2 o1 = o1s[k];
            V3 s1; s1.x = sFw[o1.x]; s1.y = sFw[o1.x+1]; s1.z = sFw[o1.x+2];
            V3 e1; e1.x = sFw[o1.y]; e1.y = sFw[o1.y+1]; e1.z = sFw[o1.y+2];

            V3 r12 = vsub(e1, s1);
            V3 r13 = vsub(s2, s1);
            V3 r14 = vsub(e2, s1);

            // f0v = r13 x r14, c1 = r12 x r13, c2 = r12 x r14
            // faces: f0v, c2, c2-c1-f0v, -c1; sign = -dot(c2, r13)
            V3 f0v = vcross(r13, r14);
            V3 c1  = vcross(r12, r13);
            V3 c2  = vcross(r12, r14);
            V3 f2  = vsub(vsub(c2, c1), f0v);

            // All dots up front -> face vectors die early (live-range cut).
            v2f q0 = vdot(f0v, f0v);
            v2f q1 = vdot(c2, c2);
            v2f q2 = vdot(f2, f2);
            v2f q3 = vdot(c1, c1);
            v2f d0 =  vdot(f0v, c2);
            v2f d1 =  vdot(c2, f2);
            v2f d2 = -vdot(f2, c1);
            v2f d3 = -vdot(c1, f0v);
            v2f sg = -vdot(c2, r13);

            v2f g = vasin_term(d0, q0 * q1)
                  + vasin_term(d1, q1 * q2)
                  + vasin_term(d2, q2 * q3)
                  + vasin_term(d3, q3 * q0);

            v2f res;
            res.x = (sg.x > 0.0f) ? g.x : -g.x;
            res.y = (sg.y > 0.0f) ? g.y : -g.y;
            sT[w][l + 64 * k] = res;
        }
    }
    __syncthreads();

    // Bin-reduce: lanes 0..24 of each wave, packed over the frame pair.
    if (l < NPAIRS) {
        int pa = (l * 205) >> 10;   // l/5 for l<25
        int pb = l - pa * 5;        // l%5
        int ia0 = c_pstart[pa], na = c_plen[pa];
        int ib0 = c_pstart[pb], nb = c_plen[pb];
        v2f s = v2f{0.0f, 0.0f};
#pragma unroll
        for (int ka = 0; ka < 4; ka++) {
#pragma unroll
            for (int kb = 0; kb < 4; kb++) {
                int idx = (ka < na && kb < nb) ? ((ia0 + ka) * 16 + (ib0 + kb)) : 256;
                s += sT[w][idx];
            }
        }
        s *= 0.07957747154594767f;  // 1/(4*pi)
        gli[(size_t)fp * GSTRIDE + l] = s.x;
        gli[(size_t)(fp + 1) * GSTRIDE + l] = s.y;
    }
}

// out[f] = max_j | gli[f+1][j]*mask[f+1] - gli[f][j]*mask[f] |
// mask[i] = ov[i-1] | ov[i] | ov[i+1]  (out-of-range -> false)
__global__ void k_out(const float* __restrict__ gli, const int* __restrict__ ov,
                      float* __restrict__ out) {
    int f = blockIdx.x * blockDim.x + threadIdx.x;
    if (f >= NFRAMES - 1) return;

    int m0 = ov[f];
    if (f > 0) m0 |= ov[f - 1];
    m0 |= ov[f + 1];

    int m1 = ov[f + 1] | ov[f];
    if (f + 2 <= NFRAMES - 1) m1 |= ov[f + 2];

    float ma = m0 ? 1.0f : 0.0f;
    float mb = m1 ? 1.0f : 0.0f;

    const float4* g0v = (const float4*)(gli + (size_t)f * GSTRIDE);        // 128B-aligned
    const float4* g1v = (const float4*)(gli + (size_t)(f + 1) * GSTRIDE);
    float v = 0.0f;
#pragma unroll
    for (int q = 0; q < 6; q++) {
        float4 u0 = g0v[q];
        float4 u1 = g1v[q];
        v = fmaxf(v, fabsf(u1.x * mb - u0.x * ma));
        v = fmaxf(v, fabsf(u1.y * mb - u0.y * ma));
        v = fmaxf(v, fabsf(u1.z * mb - u0.z * ma));
        v = fmaxf(v, fabsf(u1.w * mb - u0.w * ma));
    }
    {
        float u0 = ((const float*)g0v)[24];
        float u1 = ((const float*)g1v)[24];
        v = fmaxf(v, fabsf(u1 * mb - u0 * ma));
    }
    out[f] = v;
}

extern "C" void kernel_launch(void* const* d_in, const int* in_sizes, int n_in,
                              void* d_out, int out_size, void* d_ws, size_t ws_size,
                              hipStream_t stream) {
    const float* m1 = (const float*)d_in[0];
    const float* m2 = (const float*)d_in[1];
    float* out = (float*)d_out;

    float* gli = (float*)d_ws;                          // NFRAMES*GSTRIDE floats = 2 MB
    int* ov = (int*)(gli + (size_t)NFRAMES * GSTRIDE);  // NFRAMES ints

    k_gli<<<NFRAMES / FPB, 256, 0, stream>>>(m1, m2, gli, ov);

    {
        int threads = 256;
        int blocks = (NFRAMES - 1 + threads - 1) / threads;
        k_out<<<blocks, threads, 0, stream>>>(gli, ov, out);
    }
}